// Round 12
// baseline (59.385 us; speedup 1.0000x reference)
//
#include <hip/hip_runtime.h>

#define L 512
#define LMASK 511
#define HID 32

constexpr int THREADS        = 256;
constexpr int ROWS_PER_BLOCK = 4;
constexpr int BLOCKS_PER_B   = L / ROWS_PER_BLOCK;   // 128
constexpr int NTAB           = 4096;                 // 1/64 cells, z' in [-32,32]
constexpr int GT             = 5;                    // table groups (20 h)
constexpr int NPAIR_E        = 6;                    // exp pairs (12 h)

// Magic addressing: mantissa of (256*z' + 8194 + 2^23) = byte offset into table.
// No clamp needed: |z'|>32 has P~1e-10/eval; mask keeps reads in-table
// (wrong-but-bounded value, worst-case total error ~34 << threshold 394).
constexpr float MAGIC = 8388608.0f;                  // 2^23
constexpr float BIASB = 8194.0f;                     // 256*32 + 2 (half-cell center)

// Fused: prep + table build + stencil + hybrid table/exp2 MLP + final reduce
// (last-block-done; counter zeroed by a 4-byte memset node each launch).
__global__ __launch_bounds__(THREADS)
void site_kernel(const float* __restrict__ x,
                 const float* __restrict__ W1,
                 const float* __restrict__ b1,
                 const float* __restrict__ W2,
                 const float* __restrict__ b2,
                 float* __restrict__ partial,
                 int*   __restrict__ cnt,
                 float* __restrict__ out) {
    __shared__ __align__(16) float tab_s[NTAB];      // T(z')=1/(1+2^z'), nearest
    __shared__ __align__(16) float zw_s[GT * 16];    // table groups {wa4 wb4 wc4 w04}
    __shared__ __align__(16) float w2t_s[GT * 4];    // table-path w2
    __shared__ __align__(16) float ew_s[NPAIR_E * 8];// exp pairs {wa01 wb01 wc01 w001}
    __shared__ __align__(8)  float ew2_s[NPAIR_E * 2];

    const int t = threadIdx.x;
    const float Ke = 2.8853900817779268f;            // 2*log2(e)

    if (t < HID) {
        if (t < 4 * GT) {                            // table-path h
            const float K256 = 256.0f * Ke;
            const int g = t >> 2, q = t & 3;
            zw_s[g * 16 +  0 + q] = K256 * W1[t * 3 + 0];
            zw_s[g * 16 +  4 + q] = K256 * W1[t * 3 + 1];
            zw_s[g * 16 +  8 + q] = K256 * W1[t * 3 + 2];
            zw_s[g * 16 + 12 + q] = fmaf(K256, b1[t], BIASB + MAGIC);
            w2t_s[t] = -2.0f * W2[t];                // tanh = 1 - 2*T
        } else {                                     // exp-path h
            const int e = t - 4 * GT, p = e >> 1, q = e & 1;
            ew_s[p * 8 + 0 + q] = Ke * W1[t * 3 + 0];
            ew_s[p * 8 + 2 + q] = Ke * W1[t * 3 + 1];
            ew_s[p * 8 + 4 + q] = Ke * W1[t * 3 + 2];
            ew_s[p * 8 + 6 + q] = Ke * b1[t];
            ew2_s[p * 2 + q]    = -2.0f * W2[t];
        }
    }
    // Table entry i: T at the (half-cell-shifted) center of cell i.
    for (int i = t; i < NTAB; i += THREADS) {
        const float zp = fmaf((float)i, 0.015625f, -32.001953125f);
        tab_s[i] = __builtin_amdgcn_rcpf(1.0f + __builtin_amdgcn_exp2f(zp));
    }
    __syncthreads();

    const int blk = blockIdx.x;
    const int b   = blk >> 7;                        // / BLOCKS_PER_B
    const int i0  = (blk & (BLOCKS_PER_B - 1)) * ROWS_PER_BLOCK;
    const float* __restrict__ xb = x + (size_t)b * (L * L);

    // Features for 8 sites: rows i0..i0+3, cols t and t+256.
    float F0[8], F1[8], F2[8];
#pragma unroll
    for (int g = 0; g < 2; ++g) {
        const int j  = t + g * THREADS;
        const int jm = (j + LMASK) & LMASK, jp = (j + 1) & LMASK;

        float cc[6];                                 // center col, rows i0-1..i0+4
#pragma unroll
        for (int r = 0; r < 6; ++r) {
            const int i = (i0 + r - 1 + L) & LMASK;
            cc[r] = xb[i * L + j];
        }
#pragma unroll
        for (int s = 0; s < 4; ++s) {
            const int i   = i0 + s;
            const float lf = xb[i * L + jm];
            const float rg = xb[i * L + jp];
            const float c  = cc[s + 1];
            const float lr = lf + rg;                // == sx
            const float x1 = lr + cc[s] + cc[s + 2];
            const int k = g * 4 + s;
            F0[k] = c * c;  F1[k] = x1 * c;  F2[k] = lr * c;
        }
    }

    float acc[8] = {0.f, 0.f, 0.f, 0.f, 0.f, 0.f, 0.f, 0.f};
    const char* __restrict__ tb = (const char*)tab_s;

    // One table group (4 h x 8 sites): LDS-gather pipe.  No clamp (see BIASB).
    auto tgroup = [&](const int gq) {
        const float4 wa  = *(const float4*)&zw_s[gq * 16 + 0];
        const float4 wb  = *(const float4*)&zw_s[gq * 16 + 4];
        const float4 wc  = *(const float4*)&zw_s[gq * 16 + 8];
        const float4 w0  = *(const float4*)&zw_s[gq * 16 + 12];
        const float4 w2v = *(const float4*)&w2t_s[gq * 4];
#pragma unroll
        for (int q = 0; q < 4; ++q) {
            const float waq = ((const float*)&wa)[q];
            const float wbq = ((const float*)&wb)[q];
            const float wcq = ((const float*)&wc)[q];
            const float w0q = ((const float*)&w0)[q];
            const float w2q = ((const float*)&w2v)[q];
#pragma unroll
            for (int s = 0; s < 8; ++s) {
                const float uu = fmaf(F0[s], waq, fmaf(F1[s], wbq, fmaf(F2[s], wcq, w0q)));
                const int  off = __float_as_int(uu) & 0x3FFC;   // in-table always
                const float y  = *reinterpret_cast<const float*>(tb + off);
                acc[s] = fmaf(w2q, y, acc[s]);
            }
        }
    };
    // One exp pair (2 h x 8 sites): VALU + trans issue-port work.  No clamps:
    // pair formula saturates correctly for any reachable z (rcp(huge)->0).
    auto epair = [&](const int p) {
        const float4 e0 = *(const float4*)&ew_s[p * 8 + 0];  // wa0 wa1 wb0 wb1
        const float4 e1 = *(const float4*)&ew_s[p * 8 + 4];  // wc0 wc1 w00 w01
        const float2 w2p = *(const float2*)&ew2_s[p * 2];
        const float wa0 = e0.x, wa1 = e0.y, wb0 = e0.z, wb1 = e0.w;
        const float wc0 = e1.x, wc1 = e1.y, w00 = e1.z, w01 = e1.w;
#pragma unroll
        for (int s = 0; s < 8; ++s) {
            const float z0 = fmaf(F0[s], wa0, fmaf(F1[s], wb0, fmaf(F2[s], wc0, w00)));
            const float z1 = fmaf(F0[s], wa1, fmaf(F1[s], wb1, fmaf(F2[s], wc1, w01)));
            const float d0 = 1.0f + __builtin_amdgcn_exp2f(z0);
            const float d1 = 1.0f + __builtin_amdgcn_exp2f(z1);
            const float nm = fmaf(w2p.x, d1, w2p.y * d0); // w2a/d0+w2b/d1
            const float rr = __builtin_amdgcn_rcpf(d0 * d1);
            acc[s] = fmaf(nm, rr, acc[s]);
        }
    };

    // Fine interleave, single basic block: gather latency hides under exp work.
    tgroup(0); epair(0);
    tgroup(1); epair(1);
    tgroup(2); epair(2);
    tgroup(3); epair(3);
    tgroup(4); epair(4); epair(5);

    float a = ((acc[0] + acc[1]) + (acc[2] + acc[3]))
            + ((acc[4] + acc[5]) + (acc[6] + acc[7]));
#pragma unroll
    for (int off = 32; off > 0; off >>= 1)
        a += __shfl_down(a, off, 64);

    __shared__ float wsum[THREADS / 64];
    __shared__ int   last_s;
    const int wid = t >> 6, lane = t & 63;
    if (lane == 0) wsum[wid] = a;
    __syncthreads();
    if (t == 0) {
        partial[blk] = (wsum[0] + wsum[1]) + (wsum[2] + wsum[3]);
        __threadfence();                             // publish partial
        const int old = atomicAdd(cnt, 1);           // device-scope
        last_s = (old == (int)gridDim.x - 1);
    }
    __syncthreads();
    if (!last_s) return;

    // ---- Last block: deterministic fixed-order final reduction ----
    __threadfence();                                 // acquire all partials
    const int cb = t >> 4, k = t & 15;               // 16 configs x 16 threads
    const float* pb = partial + cb * BLOCKS_PER_B + k * 8;
    float v = 0.0f;
#pragma unroll
    for (int i = 0; i < 8; ++i) v += pb[i];
#pragma unroll
    for (int off = 8; off > 0; off >>= 1)
        v += __shfl_down(v, off, 16);
    if (k == 0) {
        float cw = b2[0];                            // + L^2*(b2 + sum_h W2[h])
        for (int h = 0; h < HID; ++h) cw += W2[h];
        out[cb] = v + 262144.0f * cw;
    }
}

extern "C" void kernel_launch(void* const* d_in, const int* in_sizes, int n_in,
                              void* d_out, int out_size, void* d_ws, size_t ws_size,
                              hipStream_t stream) {
    const float* x  = (const float*)d_in[0];
    const float* W1 = (const float*)d_in[1];
    const float* b1 = (const float*)d_in[2];
    const float* W2 = (const float*)d_in[3];
    const float* b2 = (const float*)d_in[4];
    float* out      = (float*)d_out;
    float* partial  = (float*)d_ws;                  // 2048 floats
    int*   cnt      = (int*)(partial + 2048);        // 4-byte done counter

    const int B = in_sizes[0] / (L * L);             // 16

    hipMemsetAsync(cnt, 0, sizeof(int), stream);     // graph-capturable
    site_kernel<<<B * BLOCKS_PER_B, THREADS, 0, stream>>>(
        x, W1, b1, W2, b2, partial, cnt, out);
}

// Round 13
// 34.151 us; speedup vs baseline: 1.7389x; 1.7389x over previous
//
#include <hip/hip_runtime.h>

#define L 512
#define LMASK 511
#define HID 32

constexpr int THREADS        = 256;
constexpr int ROWS_PER_BLOCK = 4;
constexpr int BLOCKS_PER_B   = L / ROWS_PER_BLOCK;   // 128
constexpr int NTAB           = 4096;                 // 1/64 cells, z' in [-32,32]
constexpr int GT             = 5;                    // table groups (20 h)
constexpr int NPAIR_E        = 6;                    // exp pairs (12 h)

// Magic addressing: mantissa of (256*z' + 8194 + 2^23) = byte offset into table.
// No clamp: |z'|>32 has P~1e-10/eval; mask keeps reads in-table (bounded error).
constexpr float MAGIC = 8388608.0f;                  // 2^23
constexpr float BIASB = 8194.0f;                     // 256*32 + 2 (half-cell center)

// Fused: per-block prep + table build + stencil + hybrid table/exp2 MLP.
__global__ __launch_bounds__(THREADS)
void site_kernel(const float* __restrict__ x,
                 const float* __restrict__ W1,
                 const float* __restrict__ b1,
                 const float* __restrict__ W2,
                 float* __restrict__ partial) {
    __shared__ __align__(16) float tab_s[NTAB];      // T(z')=1/(1+2^z'), nearest
    __shared__ __align__(16) float zw_s[GT * 16];    // table groups {wa4 wb4 wc4 w04}
    __shared__ __align__(16) float w2t_s[GT * 4];    // table-path w2
    __shared__ __align__(16) float ew_s[NPAIR_E * 8];// exp pairs {wa01 wb01 wc01 w001}
    __shared__ __align__(8)  float ew2_s[NPAIR_E * 2];

    const int t = threadIdx.x;
    const float Ke = 2.8853900817779268f;            // 2*log2(e)

    if (t < HID) {
        if (t < 4 * GT) {                            // table-path h
            const float K256 = 256.0f * Ke;
            const int g = t >> 2, q = t & 3;
            zw_s[g * 16 +  0 + q] = K256 * W1[t * 3 + 0];
            zw_s[g * 16 +  4 + q] = K256 * W1[t * 3 + 1];
            zw_s[g * 16 +  8 + q] = K256 * W1[t * 3 + 2];
            zw_s[g * 16 + 12 + q] = fmaf(K256, b1[t], BIASB + MAGIC);
            w2t_s[t] = -2.0f * W2[t];                // tanh = 1 - 2*T
        } else {                                     // exp-path h
            const int e = t - 4 * GT, p = e >> 1, q = e & 1;
            ew_s[p * 8 + 0 + q] = Ke * W1[t * 3 + 0];
            ew_s[p * 8 + 2 + q] = Ke * W1[t * 3 + 1];
            ew_s[p * 8 + 4 + q] = Ke * W1[t * 3 + 2];
            ew_s[p * 8 + 6 + q] = Ke * b1[t];
            ew2_s[p * 2 + q]    = -2.0f * W2[t];
        }
    }
    // Table entry i: T at the (half-cell-shifted) center of cell i.
    for (int i = t; i < NTAB; i += THREADS) {
        const float zp = fmaf((float)i, 0.015625f, -32.001953125f);
        tab_s[i] = __builtin_amdgcn_rcpf(1.0f + __builtin_amdgcn_exp2f(zp));
    }
    __syncthreads();

    const int blk = blockIdx.x;
    const int b   = blk >> 7;                        // / BLOCKS_PER_B
    const int i0  = (blk & (BLOCKS_PER_B - 1)) * ROWS_PER_BLOCK;
    const float* __restrict__ xb = x + (size_t)b * (L * L);

    // Features for 8 sites: rows i0..i0+3, cols t and t+256.
    float F0[8], F1[8], F2[8];
#pragma unroll
    for (int g = 0; g < 2; ++g) {
        const int j  = t + g * THREADS;
        const int jm = (j + LMASK) & LMASK, jp = (j + 1) & LMASK;

        float cc[6];                                 // center col, rows i0-1..i0+4
#pragma unroll
        for (int r = 0; r < 6; ++r) {
            const int i = (i0 + r - 1 + L) & LMASK;
            cc[r] = xb[i * L + j];
        }
#pragma unroll
        for (int s = 0; s < 4; ++s) {
            const int i   = i0 + s;
            const float lf = xb[i * L + jm];
            const float rg = xb[i * L + jp];
            const float c  = cc[s + 1];
            const float lr = lf + rg;                // == sx
            const float x1 = lr + cc[s] + cc[s + 2];
            const int k = g * 4 + s;
            F0[k] = c * c;  F1[k] = x1 * c;  F2[k] = lr * c;
        }
    }

    float acc[8] = {0.f, 0.f, 0.f, 0.f, 0.f, 0.f, 0.f, 0.f};
    const char* __restrict__ tb = (const char*)tab_s;

    // One table group (4 h x 8 sites): LDS-gather pipe.  No clamp (mask-only).
    auto tgroup = [&](const int gq) {
        const float4 wa  = *(const float4*)&zw_s[gq * 16 + 0];
        const float4 wb  = *(const float4*)&zw_s[gq * 16 + 4];
        const float4 wc  = *(const float4*)&zw_s[gq * 16 + 8];
        const float4 w0  = *(const float4*)&zw_s[gq * 16 + 12];
        const float4 w2v = *(const float4*)&w2t_s[gq * 4];
#pragma unroll
        for (int q = 0; q < 4; ++q) {
            const float waq = ((const float*)&wa)[q];
            const float wbq = ((const float*)&wb)[q];
            const float wcq = ((const float*)&wc)[q];
            const float w0q = ((const float*)&w0)[q];
            const float w2q = ((const float*)&w2v)[q];
#pragma unroll
            for (int s = 0; s < 8; ++s) {
                const float uu = fmaf(F0[s], waq, fmaf(F1[s], wbq, fmaf(F2[s], wcq, w0q)));
                const int  off = __float_as_int(uu) & 0x3FFC;   // in-table always
                const float y  = *reinterpret_cast<const float*>(tb + off);
                acc[s] = fmaf(w2q, y, acc[s]);
            }
        }
    };
    // One exp pair (2 h x 8 sites): VALU + trans issue-port work.  No clamps:
    // the pair formula saturates correctly for any reachable z.
    auto epair = [&](const int p) {
        const float4 e0 = *(const float4*)&ew_s[p * 8 + 0];  // wa0 wa1 wb0 wb1
        const float4 e1 = *(const float4*)&ew_s[p * 8 + 4];  // wc0 wc1 w00 w01
        const float2 w2p = *(const float2*)&ew2_s[p * 2];
        const float wa0 = e0.x, wa1 = e0.y, wb0 = e0.z, wb1 = e0.w;
        const float wc0 = e1.x, wc1 = e1.y, w00 = e1.z, w01 = e1.w;
#pragma unroll
        for (int s = 0; s < 8; ++s) {
            const float z0 = fmaf(F0[s], wa0, fmaf(F1[s], wb0, fmaf(F2[s], wc0, w00)));
            const float z1 = fmaf(F0[s], wa1, fmaf(F1[s], wb1, fmaf(F2[s], wc1, w01)));
            const float d0 = 1.0f + __builtin_amdgcn_exp2f(z0);
            const float d1 = 1.0f + __builtin_amdgcn_exp2f(z1);
            const float nm = fmaf(w2p.x, d1, w2p.y * d0); // w2a/d0+w2b/d1
            const float rr = __builtin_amdgcn_rcpf(d0 * d1);
            acc[s] = fmaf(nm, rr, acc[s]);
        }
    };

    // Fine interleave, single basic block: gather latency hides under exp work.
    tgroup(0); epair(0);
    tgroup(1); epair(1);
    tgroup(2); epair(2);
    tgroup(3); epair(3);
    tgroup(4); epair(4); epair(5);

    float a = ((acc[0] + acc[1]) + (acc[2] + acc[3]))
            + ((acc[4] + acc[5]) + (acc[6] + acc[7]));
#pragma unroll
    for (int off = 32; off > 0; off >>= 1)
        a += __shfl_down(a, off, 64);

    __shared__ float wsum[THREADS / 64];
    const int wid = t >> 6, lane = t & 63;
    if (lane == 0) wsum[wid] = a;
    __syncthreads();
    if (t == 0)
        partial[blk] = (wsum[0] + wsum[1]) + (wsum[2] + wsum[3]);
}

// Deterministic fixed-order reduction + folded tanh constant.
__global__ __launch_bounds__(128)
void reduce_kernel(const float* __restrict__ partial,
                   const float* __restrict__ W2,
                   const float* __restrict__ b2,
                   float* __restrict__ out) {
    const int b = blockIdx.x, t = threadIdx.x;
    const float NS = (float)(L * L);                 // 262144 sites per config

    float v = partial[b * BLOCKS_PER_B + t];
    if (t < HID) v += NS * W2[t];                    // + L^2 * sum_h W2[h]
    if (t == 0)  v += NS * b2[0];                    // + L^2 * b2

#pragma unroll
    for (int off = 32; off > 0; off >>= 1)
        v += __shfl_down(v, off, 64);

    __shared__ float ws2[2];
    if ((t & 63) == 0) ws2[t >> 6] = v;
    __syncthreads();
    if (t == 0) out[b] = ws2[0] + ws2[1];
}

extern "C" void kernel_launch(void* const* d_in, const int* in_sizes, int n_in,
                              void* d_out, int out_size, void* d_ws, size_t ws_size,
                              hipStream_t stream) {
    const float* x  = (const float*)d_in[0];
    const float* W1 = (const float*)d_in[1];
    const float* b1 = (const float*)d_in[2];
    const float* W2 = (const float*)d_in[3];
    const float* b2 = (const float*)d_in[4];
    float* out      = (float*)d_out;
    float* partial  = (float*)d_ws;                  // 2048 floats

    const int B = in_sizes[0] / (L * L);             // 16

    site_kernel<<<B * BLOCKS_PER_B, THREADS, 0, stream>>>(x, W1, b1, W2, partial);
    reduce_kernel<<<B, 128, 0, stream>>>(partial, W2, b2, out);
}

// Round 14
// 32.473 us; speedup vs baseline: 1.8287x; 1.0517x over previous
//
#include <hip/hip_runtime.h>

#define L 512
#define LMASK 511
#define HID 32

constexpr int THREADS        = 256;
constexpr int ROWS_PER_BLOCK = 4;
constexpr int BLOCKS_PER_B   = L / ROWS_PER_BLOCK;   // 128
constexpr int NPAIR          = HID / 2;              // 16 exp pairs

using v2f = __attribute__((ext_vector_type(2))) float;

// Pure-exp MLP, site-packed float2 (v_pk_*_f32), single-pipe (VALU issue).
// tanh(y) = 1 - 2/(1+e^{2y}); pair-rcp: w2a/d0 + w2b/d1 = (w2a*d1+w2b*d0)/(d0*d1)
// Unclamped is safe: d in [1, 1+2^~60] -> product < 2^120 < inf (validated R13).
__global__ __launch_bounds__(THREADS)
void site_kernel(const float* __restrict__ x,
                 const float* __restrict__ W1,
                 const float* __restrict__ b1,
                 const float* __restrict__ W2,
                 float* __restrict__ partial) {
    __shared__ __align__(16) float ew_s[NPAIR * 8];  // {wa01 wb01 wc01 w001} per pair
    __shared__ __align__(8)  float ew2_s[NPAIR * 2]; // -2*W2 per pair

    const int t = threadIdx.x;
    const float Ke = 2.8853900817779268f;            // 2*log2(e)

    if (t < HID) {
        const int p = t >> 1, q = t & 1;
        ew_s[p * 8 + 0 + q] = Ke * W1[t * 3 + 0];
        ew_s[p * 8 + 2 + q] = Ke * W1[t * 3 + 1];
        ew_s[p * 8 + 4 + q] = Ke * W1[t * 3 + 2];
        ew_s[p * 8 + 6 + q] = Ke * b1[t];
        ew2_s[p * 2 + q]    = -2.0f * W2[t];         // tanh = 1 - 2*T
    }
    __syncthreads();

    const int blk = blockIdx.x;
    const int b   = blk >> 7;                        // / BLOCKS_PER_B
    const int i0  = (blk & (BLOCKS_PER_B - 1)) * ROWS_PER_BLOCK;
    const float* __restrict__ xb = x + (size_t)b * (L * L);

    // Features for 8 sites: rows i0..i0+3, cols t and t+256.
    float F0[8], F1[8], F2[8];
#pragma unroll
    for (int g = 0; g < 2; ++g) {
        const int j  = t + g * THREADS;
        const int jm = (j + LMASK) & LMASK, jp = (j + 1) & LMASK;

        float cc[6];                                 // center col, rows i0-1..i0+4
#pragma unroll
        for (int r = 0; r < 6; ++r) {
            const int i = (i0 + r - 1 + L) & LMASK;
            cc[r] = xb[i * L + j];
        }
#pragma unroll
        for (int s = 0; s < 4; ++s) {
            const int i   = i0 + s;
            const float lf = xb[i * L + jm];
            const float rg = xb[i * L + jp];
            const float c  = cc[s + 1];
            const float lr = lf + rg;                // == sx
            const float x1 = lr + cc[s] + cc[s + 2];
            const int k = g * 4 + s;
            F0[k] = c * c;  F1[k] = x1 * c;  F2[k] = lr * c;
        }
    }

    // Pack sites into duos: duo d = sites (2d, 2d+1).
    v2f F0v[4], F1v[4], F2v[4];
#pragma unroll
    for (int d = 0; d < 4; ++d) {
        F0v[d] = v2f{F0[2 * d], F0[2 * d + 1]};
        F1v[d] = v2f{F1[2 * d], F1[2 * d + 1]};
        F2v[d] = v2f{F2[2 * d], F2[2 * d + 1]};
    }

    v2f acc0 = {0.f, 0.f}, acc1 = {0.f, 0.f}, acc2 = {0.f, 0.f}, acc3 = {0.f, 0.f};
    const v2f one = {1.0f, 1.0f};

#pragma unroll 1
    for (int p = 0; p < NPAIR; ++p) {
        const float4 e0 = *(const float4*)&ew_s[p * 8 + 0];  // wa0 wa1 wb0 wb1
        const float4 e1 = *(const float4*)&ew_s[p * 8 + 4];  // wc0 wc1 w00 w01
        const float2 wp = *(const float2*)&ew2_s[p * 2];
        const v2f waa0 = {e0.x, e0.x}, waa1 = {e0.y, e0.y};
        const v2f wbb0 = {e0.z, e0.z}, wbb1 = {e0.w, e0.w};
        const v2f wcc0 = {e1.x, e1.x}, wcc1 = {e1.y, e1.y};
        const v2f w000 = {e1.z, e1.z}, w001 = {e1.w, e1.w};
        const v2f w2xx = {wp.x, wp.x}, w2yy = {wp.y, wp.y};

#pragma unroll
        for (int d = 0; d < 4; ++d) {
            const v2f z0 = __builtin_elementwise_fma(F0v[d], waa0,
                           __builtin_elementwise_fma(F1v[d], wbb0,
                           __builtin_elementwise_fma(F2v[d], wcc0, w000)));
            const v2f z1 = __builtin_elementwise_fma(F0v[d], waa1,
                           __builtin_elementwise_fma(F1v[d], wbb1,
                           __builtin_elementwise_fma(F2v[d], wcc1, w001)));
            const v2f ex0 = {__builtin_amdgcn_exp2f(z0.x), __builtin_amdgcn_exp2f(z0.y)};
            const v2f ex1 = {__builtin_amdgcn_exp2f(z1.x), __builtin_amdgcn_exp2f(z1.y)};
            const v2f d0 = ex0 + one;
            const v2f d1 = ex1 + one;
            const v2f nm = __builtin_elementwise_fma(w2yy, d0, w2xx * d1);
            const v2f D  = d0 * d1;
            const v2f rr = {__builtin_amdgcn_rcpf(D.x), __builtin_amdgcn_rcpf(D.y)};
            const v2f contrib = nm * rr;
            if      (d == 0) acc0 += contrib;
            else if (d == 1) acc1 += contrib;
            else if (d == 2) acc2 += contrib;
            else             acc3 += contrib;
        }
    }

    float a = ((acc0.x + acc0.y) + (acc1.x + acc1.y))
            + ((acc2.x + acc2.y) + (acc3.x + acc3.y));
#pragma unroll
    for (int off = 32; off > 0; off >>= 1)
        a += __shfl_down(a, off, 64);

    __shared__ float wsum[THREADS / 64];
    const int wid = t >> 6, lane = t & 63;
    if (lane == 0) wsum[wid] = a;
    __syncthreads();
    if (t == 0)
        partial[blk] = (wsum[0] + wsum[1]) + (wsum[2] + wsum[3]);
}

// Deterministic fixed-order reduction + folded tanh constant.
__global__ __launch_bounds__(128)
void reduce_kernel(const float* __restrict__ partial,
                   const float* __restrict__ W2,
                   const float* __restrict__ b2,
                   float* __restrict__ out) {
    const int b = blockIdx.x, t = threadIdx.x;
    const float NS = (float)(L * L);                 // 262144 sites per config

    float v = partial[b * BLOCKS_PER_B + t];
    if (t < HID) v += NS * W2[t];                    // + L^2 * sum_h W2[h]
    if (t == 0)  v += NS * b2[0];                    // + L^2 * b2

#pragma unroll
    for (int off = 32; off > 0; off >>= 1)
        v += __shfl_down(v, off, 64);

    __shared__ float ws2[2];
    if ((t & 63) == 0) ws2[t >> 6] = v;
    __syncthreads();
    if (t == 0) out[b] = ws2[0] + ws2[1];
}

extern "C" void kernel_launch(void* const* d_in, const int* in_sizes, int n_in,
                              void* d_out, int out_size, void* d_ws, size_t ws_size,
                              hipStream_t stream) {
    const float* x  = (const float*)d_in[0];
    const float* W1 = (const float*)d_in[1];
    const float* b1 = (const float*)d_in[2];
    const float* W2 = (const float*)d_in[3];
    const float* b2 = (const float*)d_in[4];
    float* out      = (float*)d_out;
    float* partial  = (float*)d_ws;                  // 2048 floats

    const int B = in_sizes[0] / (L * L);             // 16

    site_kernel<<<B * BLOCKS_PER_B, THREADS, 0, stream>>>(x, W1, b1, W2, partial);
    reduce_kernel<<<B, 128, 0, stream>>>(partial, W2, b2, out);
}